// Round 20
// baseline (80.406 us; speedup 1.0000x reference)
//
#include <hip/hip_runtime.h>
#include <hip/hip_bf16.h>

#define NB 32
#define NS 2048
#define ND 64
#define NDK 24
#define NDV 32
#define LOG2E 1.4426950408889634f

typedef __attribute__((ext_vector_type(8))) short short8;
typedef __attribute__((ext_vector_type(4))) float f32x4;

typedef __attribute__((address_space(3))) unsigned int lds_u32;
typedef __attribute__((address_space(1))) const unsigned int glb_u32;

#define LFENCE asm volatile("" ::: "memory")

__device__ __forceinline__ void cp16(const void* g, void* l) {
  __builtin_amdgcn_global_load_lds((glb_u32*)g, (lds_u32*)l, 16, 0, 0);
}

__device__ __forceinline__ float fexp2(float x) {  // raw v_exp_f32
  return __builtin_amdgcn_exp2f(x);
}

__device__ __forceinline__ unsigned pk2(float a, float b) {
  __hip_bfloat16 ha = __float2bfloat16(a), hb = __float2bfloat16(b);
  return ((unsigned)__builtin_bit_cast(unsigned short, hb) << 16) |
         (unsigned)__builtin_bit_cast(unsigned short, ha);
}

__device__ __forceinline__ unsigned pku(__hip_bfloat16 lo, __hip_bfloat16 hi) {
  return ((unsigned)__builtin_bit_cast(unsigned short, hi) << 16) |
         (unsigned)__builtin_bit_cast(unsigned short, lo);
}

// Fragment-order global layouts (16x16 frags, 1024 B = 512 bf16 each):
//   qfb/kfb: [b][tile(32)][frag(4)][lane][8]   frag = row-16-group within tile
//   vfb:     [b][tile(32)][kc*2+vs][lane][8]   col v=vs*16+l15, t=kc*32+lg*8..
//   whT:     [dt(4)][lane][8]                  col d=dt*16+l15, k: v=lg*8..

// ---------------- Kernel 0: pack weights once (1 block) ----------------
__global__ __launch_bounds__(256) void prep_kernel(
    const float* __restrict__ Wq, const float* __restrict__ Wk,
    const float* __restrict__ Wv, const float* __restrict__ Wh,
    __hip_bfloat16* __restrict__ wt, __hip_bfloat16* __restrict__ whT) {
  const int tid = threadIdx.x;
  for (int o = tid; o < 6144; o += 256) {
    const int n = o / 72, d = o % 72;
    float val = 0.f;
    if (o < 5760 && d < ND) {
      if (n < 24)      val = Wq[d * NDK + n] * LOG2E;
      else if (n < 48) val = Wk[d * NDK + (n - 24)];
      else             val = Wv[d * NDV + (n - 48)];
    }
    wt[o] = __float2bfloat16(val);
  }
  {
    const int lane = tid & 63, l15 = lane & 15, lg = lane >> 4;
    const int d = (tid >> 6) * 16 + l15;
    uint4 u;
    u.x = pk2(Wh[(lg * 8 + 0) * ND + d], Wh[(lg * 8 + 1) * ND + d]);
    u.y = pk2(Wh[(lg * 8 + 2) * ND + d], Wh[(lg * 8 + 3) * ND + d]);
    u.z = pk2(Wh[(lg * 8 + 4) * ND + d], Wh[(lg * 8 + 5) * ND + d]);
    u.w = pk2(Wh[(lg * 8 + 6) * ND + d], Wh[(lg * 8 + 7) * ND + d]);
    ((uint4*)whT)[tid] = u;
  }
}

// ---------------- Kernel 1: projections via MFMA, fragment-order outputs ----
__global__ __launch_bounds__(256) void proj_kernel(
    const float* __restrict__ x, const __hip_bfloat16* __restrict__ wt,
    __hip_bfloat16* __restrict__ qfb, __hip_bfloat16* __restrict__ kfb,
    __hip_bfloat16* __restrict__ vfb) {
  __shared__ __hip_bfloat16 xsb[64 * 72];
  __shared__ __hip_bfloat16 Wt[6144];
  __shared__ __hip_bfloat16 os[64][81];

  const int tid = threadIdx.x;
  const size_t row0 = (size_t)blockIdx.x * 64;
  const int b = (int)(row0 >> 11);
  const int tile = (int)((row0 >> 6) & 31);
  const int wv = tid >> 6, lane = tid & 63;
  const int l15 = lane & 15, lg = lane >> 4;

  #pragma unroll
  for (int i = 0; i < 3; ++i)
    cp16((const char*)wt + (i * 256 + tid) * 16, (char*)Wt + (i * 256 + tid) * 16);

  {
    const int r = tid >> 2, c16 = (tid & 3) * 16;
    const float4* src = (const float4*)(x + (row0 + r) * ND + c16);
    unsigned u[8];
    #pragma unroll
    for (int i = 0; i < 4; ++i) {
      float4 f = src[i];
      u[2 * i] = pk2(f.x, f.y);
      u[2 * i + 1] = pk2(f.z, f.w);
    }
    uint4* dst = (uint4*)((char*)xsb + r * 144 + c16 * 2);
    dst[0] = make_uint4(u[0], u[1], u[2], u[3]);
    dst[1] = make_uint4(u[4], u[5], u[6], u[7]);
  }
  __syncthreads();

  {
    short8 a[2];
    #pragma unroll
    for (int kc = 0; kc < 2; ++kc)
      a[kc] = *(const short8*)((char*)xsb + ((wv * 16 + l15) * 72 + kc * 32 + lg * 8) * 2);
    const f32x4 z = {0.f, 0.f, 0.f, 0.f};
    #pragma unroll
    for (int nt = 0; nt < 5; ++nt) {
      f32x4 acc = z;
      #pragma unroll
      for (int kc = 0; kc < 2; ++kc) {
        const short8 bfr = *(const short8*)((char*)Wt + ((nt * 16 + l15) * 72 + kc * 32 + lg * 8) * 2);
        acc = __builtin_amdgcn_mfma_f32_16x16x32_bf16(a[kc], bfr, acc, 0, 0, 0);
      }
      #pragma unroll
      for (int r = 0; r < 4; ++r)
        os[wv * 16 + lg * 4 + r][nt * 16 + l15] = __float2bfloat16(acc[r]);
    }
  }
  __syncthreads();

  const size_t fbase = ((size_t)(b * 32 + tile)) * 4 * 256;  // in u32 units
  for (int j = tid; j < 2048; j += 256) {
    const int arr = j >> 10, jj = j & 1023;
    const int qs = jj >> 8, ln = (jj >> 2) & 63, wd = jj & 3;
    const int row = qs * 16 + (ln & 15);
    const int c0 = (ln >> 4) * 8 + wd * 2;
    unsigned u = 0;
    if (c0 < 24) u = pku(os[row][arr * 24 + c0], os[row][arr * 24 + c0 + 1]);
    unsigned* dst = (unsigned*)(arr ? kfb : qfb);
    dst[fbase + (size_t)qs * 256 + ln * 4 + wd] = u;
  }
  for (int j = tid; j < 1024; j += 256) {
    const int fi = j >> 8;                  // kc*2+vs
    const int ln = (j >> 2) & 63, wd = j & 3;
    const int v = (fi & 1) * 16 + (ln & 15);
    const int tl = (fi >> 1) * 32 + (ln >> 4) * 8 + wd * 2;
    const unsigned u = pku(os[tl][48 + v], os[tl + 1][48 + v]);
    ((unsigned*)vfb)[fbase + (size_t)fi * 256 + ln * 4 + wd] = u;
  }
}

// ---------------- Kernel 2: stats — R14 config + per-iter wave phase-lock ----
struct QT { short8 q0, q1, q2, q3; };

__device__ __forceinline__ void loadQ(QT& t, const __hip_bfloat16* qp, int it, int lane) {
  const __hip_bfloat16* p = qp + (size_t)it * 2048 + lane * 8;
  t.q0 = *(const short8*)(p);
  t.q1 = *(const short8*)(p + 512);
  t.q2 = *(const short8*)(p + 1024);
  t.q3 = *(const short8*)(p + 1536);
}

__device__ __forceinline__ void accQ(const QT& t, short8 kf0, short8 kf1,
                                     f32x4& s0, f32x4& s1) {
  const f32x4 z = {0.f, 0.f, 0.f, 0.f};
  #pragma unroll
  for (int qi = 0; qi < 4; ++qi) {
    const short8 q = qi == 0 ? t.q0 : qi == 1 ? t.q1 : qi == 2 ? t.q2 : t.q3;
    f32x4 d0 = __builtin_amdgcn_mfma_f32_16x16x32_bf16(kf0, q, z, 0, 0, 0);
    f32x4 d1 = __builtin_amdgcn_mfma_f32_16x16x32_bf16(kf1, q, z, 0, 0, 0);
    #pragma unroll
    for (int r = 0; r < 4; ++r) { s0[r] += fexp2(d0[r]); s1[r] += fexp2(d1[r]); }
  }
}

__global__ __launch_bounds__(256) void stats_kernel(
    const __hip_bfloat16* __restrict__ qfb, const __hip_bfloat16* __restrict__ kfb,
    float* __restrict__ ls) {
  const int g = blockIdx.x;
  const int xcd = g & 7, loc = g >> 3;      // 512 = 8 xcd * 64
  const int b = (xcd << 2) + (loc >> 4);
  const int tg = loc & 15;
  const int tid = threadIdx.x;
  const int wv = tid >> 6, lane = tid & 63;
  const int l15 = lane & 15, lg = lane >> 4;
  const int tile_t = tg * 2 + (wv >> 1);
  const int ib = (wv & 1) * 2;

  short8 kf[2];
  #pragma unroll
  for (int j = 0; j < 2; ++j)
    kf[j] = *(const short8*)(kfb + (((size_t)(b * 32 + tile_t)) * 4 + ib + j) * 512 + lane * 8);

  const __hip_bfloat16* qp = qfb + (size_t)b * 32 * 2048;
  const f32x4 z = {0.f, 0.f, 0.f, 0.f};
  f32x4 s0 = z, s1 = z;

  QT A, B;
  loadQ(A, qp, 0, lane);
  for (int it2 = 0; it2 < 16; ++it2) {
    // phase-lock the 4 waves: their Q-load streams are identical, so lockstep
    // lets wave0's L1 fill serve waves 1-3 (no cross-wave memory deps -> safe)
    __builtin_amdgcn_s_barrier();
    const int itA = it2 * 2;
    loadQ(B, qp, itA + 1, lane);
    accQ(A, kf[0], kf[1], s0, s1);
    loadQ(A, qp, itA + 2 < 32 ? itA + 2 : 31, lane);
    accQ(B, kf[0], kf[1], s0, s1);
  }
  #pragma unroll
  for (int m = 1; m < 16; m <<= 1) {
    #pragma unroll
    for (int r = 0; r < 4; ++r) {
      s0[r] += __shfl_xor(s0[r], m);
      s1[r] += __shfl_xor(s1[r], m);
    }
  }
  if (l15 == 0) {
    f32x4 o0, o1;
    #pragma unroll
    for (int r = 0; r < 4; ++r) { o0[r] = -__log2f(s0[r]); o1[r] = -__log2f(s1[r]); }
    float* lp = ls + ((size_t)b << 11) + tile_t * 64 + ib * 16 + lg * 4;
    *(f32x4*)(lp) = o0;
    *(f32x4*)(lp + 16) = o1;
  }
}

// ---------------- Kernel 3: attn — R14 base + per-iter wave phase-lock -------
struct KVT {
  short8 k0, k1, k2, k3;
  short8 v0, v1, v2, v3;
  f32x4 l0, l1, l2, l3;
};

__device__ __forceinline__ void loadKV(KVT& t, const __hip_bfloat16* kp0,
    const __hip_bfloat16* vp0, const float* lsb, int it, int lane, int lg) {
  const __hip_bfloat16* kp = kp0 + (size_t)it * 2048 + lane * 8;
  t.k0 = *(const short8*)(kp);
  t.k1 = *(const short8*)(kp + 512);
  t.k2 = *(const short8*)(kp + 1024);
  t.k3 = *(const short8*)(kp + 1536);
  const __hip_bfloat16* vp = vp0 + (size_t)it * 2048 + lane * 8;
  t.v0 = *(const short8*)(vp);
  t.v1 = *(const short8*)(vp + 512);
  t.v2 = *(const short8*)(vp + 1024);
  t.v3 = *(const short8*)(vp + 1536);
  const float* lp = lsb + it * 64 + lg * 4;
  t.l0 = *(const f32x4*)(lp);
  t.l1 = *(const f32x4*)(lp + 16);
  t.l2 = *(const f32x4*)(lp + 32);
  t.l3 = *(const f32x4*)(lp + 48);
}

// per-wave P region: 16 rows (q) x 176 B
__device__ __forceinline__ void computeKV(const KVT& t, short8 qf, char* Pw,
                                          int lg, f32x4& h10, f32x4& h11) {
  f32x4 d;
  uint2 w;
  d = __builtin_amdgcn_mfma_f32_16x16x32_bf16(t.k0, qf, t.l0, 0, 0, 0);
  w.x = pk2(fexp2(d[0]), fexp2(d[1]));
  w.y = pk2(fexp2(d[2]), fexp2(d[3]));
  *(uint2*)(Pw + lg * 8) = w;
  d = __builtin_amdgcn_mfma_f32_16x16x32_bf16(t.k1, qf, t.l1, 0, 0, 0);
  w.x = pk2(fexp2(d[0]), fexp2(d[1]));
  w.y = pk2(fexp2(d[2]), fexp2(d[3]));
  *(uint2*)(Pw + 32 + lg * 8) = w;
  d = __builtin_amdgcn_mfma_f32_16x16x32_bf16(t.k2, qf, t.l2, 0, 0, 0);
  w.x = pk2(fexp2(d[0]), fexp2(d[1]));
  w.y = pk2(fexp2(d[2]), fexp2(d[3]));
  *(uint2*)(Pw + 64 + lg * 8) = w;
  d = __builtin_amdgcn_mfma_f32_16x16x32_bf16(t.k3, qf, t.l3, 0, 0, 0);
  w.x = pk2(fexp2(d[0]), fexp2(d[1]));
  w.y = pk2(fexp2(d[2]), fexp2(d[3]));
  *(uint2*)(Pw + 96 + lg * 8) = w;
  LFENCE;  // pin P ds_write -> ds_read order (same wave, in-order DS pipe)
  const short8 p0 = *(const short8*)(Pw + lg * 16);
  const short8 p1 = *(const short8*)(Pw + 64 + lg * 16);
  h10 = __builtin_amdgcn_mfma_f32_16x16x32_bf16(p0, t.v0, h10, 0, 0, 0);
  h11 = __builtin_amdgcn_mfma_f32_16x16x32_bf16(p0, t.v1, h11, 0, 0, 0);
  h10 = __builtin_amdgcn_mfma_f32_16x16x32_bf16(p1, t.v2, h10, 0, 0, 0);
  h11 = __builtin_amdgcn_mfma_f32_16x16x32_bf16(p1, t.v3, h11, 0, 0, 0);
  LFENCE;  // keep next block's P writes after these reads
}

__global__ __launch_bounds__(256) void attn_kernel(
    const __hip_bfloat16* __restrict__ qfb, const __hip_bfloat16* __restrict__ kfb,
    const __hip_bfloat16* __restrict__ vfb, const float* __restrict__ ls,
    const __hip_bfloat16* __restrict__ whT, float* __restrict__ out) {
  __shared__ char Ps[4 * 2816];   // 4 waves x 16 rows x 176 B

  const int g = blockIdx.x;
  const int xcd = g & 7, loc = g >> 3;      // 512 = 8 xcd * 64
  const int b = (xcd << 2) + (loc >> 4);
  const int qg = loc & 15;
  const int tid = threadIdx.x;
  const int wv = tid >> 6, lane = tid & 63;
  const int l15 = lane & 15, lg = lane >> 4;
  const int tile_q = qg * 2 + (wv >> 1);
  const int ib = (wv & 1) * 2;

  char* Pw = Ps + wv * 2816 + l15 * 176;

  short8 qf[2];
  #pragma unroll
  for (int qi = 0; qi < 2; ++qi)
    qf[qi] = *(const short8*)(qfb + (((size_t)(b * 32 + tile_q)) * 4 + ib + qi) * 512 + lane * 8);

  const __hip_bfloat16* kp0 = kfb + (size_t)b * 32 * 2048;
  const __hip_bfloat16* vp0 = vfb + (size_t)b * 32 * 2048;
  const float* lsb = ls + ((size_t)b << 11);

  const f32x4 z = {0.f, 0.f, 0.f, 0.f};
  f32x4 h1[2][2] = {{z, z}, {z, z}};

  KVT A, B;
  loadKV(A, kp0, vp0, lsb, 0, lane, lg);
  for (int it2 = 0; it2 < 16; ++it2) {
    // phase-lock the 4 waves: their K/V/ls load streams are byte-identical,
    // so lockstep turns waves 1-3's misses into L1 hits / MSHR coalesces.
    // No cross-wave memory deps (P strictly per-wave) -> raw barrier is safe.
    __builtin_amdgcn_s_barrier();
    const int itA = it2 * 2;
    loadKV(B, kp0, vp0, lsb, itA + 1, lane, lg);
    computeKV(A, qf[0], Pw, lg, h1[0][0], h1[0][1]);
    computeKV(A, qf[1], Pw, lg, h1[1][0], h1[1][1]);
    loadKV(A, kp0, vp0, lsb, itA + 2 < 32 ? itA + 2 : 31, lane, lg);
    computeKV(B, qf[0], Pw, lg, h1[0][0], h1[0][1]);
    computeKV(B, qf[1], Pw, lg, h1[1][0], h1[1][1]);
  }

  // epilogue: out = h1 @ Wh per q-frag (per-wave region, no barrier needed)
  short8 wf[4];
  #pragma unroll
  for (int dt = 0; dt < 4; ++dt)
    wf[dt] = *(const short8*)(whT + dt * 512 + lane * 8);
  #pragma unroll
  for (int qi = 0; qi < 2; ++qi) {
    #pragma unroll
    for (int vs = 0; vs < 2; ++vs)
      #pragma unroll
      for (int r = 0; r < 4; ++r)
        *(unsigned short*)(Ps + wv * 2816 + (lg * 4 + r) * 176 + (vs * 16 + l15) * 2) =
            __builtin_bit_cast(unsigned short, __float2bfloat16(h1[qi][vs][r]));
    LFENCE;
    const short8 hf = *(const short8*)(Pw + lg * 16);
    float* ob = out + (size_t)(b * NS + tile_q * 64 + (ib + qi) * 16 + lg * 4) * ND + l15;
    #pragma unroll
    for (int dt = 0; dt < 4; ++dt) {
      f32x4 o = __builtin_amdgcn_mfma_f32_16x16x32_bf16(hf, wf[dt], z, 0, 0, 0);
      float* op = ob + dt * 16;
      op[0] = o[0];
      op[ND] = o[1];
      op[2 * ND] = o[2];
      op[3 * ND] = o[3];
    }
    LFENCE;
  }
}

// ---------------- launcher ----------------
extern "C" void kernel_launch(void* const* d_in, const int* in_sizes, int n_in,
                              void* d_out, int out_size, void* d_ws, size_t ws_size,
                              hipStream_t stream) {
  const float* x  = (const float*)d_in[0];
  const float* Wq = (const float*)d_in[1];
  const float* Wk = (const float*)d_in[2];
  const float* Wv = (const float*)d_in[3];
  const float* Wh = (const float*)d_in[4];
  float* out = (float*)d_out;

  char* ws = (char*)d_ws;
  __hip_bfloat16* qfb = (__hip_bfloat16*)ws;                   // 4 MB
  __hip_bfloat16* kfb = (__hip_bfloat16*)(ws + 4194304);       // 4 MB
  __hip_bfloat16* vfb = (__hip_bfloat16*)(ws + 8388608);       // 4 MB
  float*          lsp = (float*)(ws + 12582912);               // 256 KB
  __hip_bfloat16* whT = (__hip_bfloat16*)(ws + 12845056);      // 4 KB
  __hip_bfloat16* wt  = (__hip_bfloat16*)(ws + 12849152);      // 12 KB

  hipLaunchKernelGGL(prep_kernel, dim3(1), dim3(256), 0, stream,
                     Wq, Wk, Wv, Wh, wt, whT);
  hipLaunchKernelGGL(proj_kernel, dim3(1024), dim3(256), 0, stream,
                     x, wt, qfb, kfb, vfb);
  hipLaunchKernelGGL(stats_kernel, dim3(512), dim3(256), 0, stream,
                     qfb, kfb, lsp);
  hipLaunchKernelGGL(attn_kernel, dim3(512), dim3(256), 0, stream,
                     qfb, kfb, vfb, lsp, whT, out);
}

// Round 21
// 77.375 us; speedup vs baseline: 1.0392x; 1.0392x over previous
//
#include <hip/hip_runtime.h>
#include <hip/hip_bf16.h>

#define NB 32
#define NS 2048
#define ND 64
#define NDK 24
#define NDV 32
#define LOG2E 1.4426950408889634f

typedef __attribute__((ext_vector_type(8))) short short8;
typedef __attribute__((ext_vector_type(4))) float f32x4;

typedef __attribute__((address_space(3))) unsigned int lds_u32;
typedef __attribute__((address_space(1))) const unsigned int glb_u32;

#define LFENCE asm volatile("" ::: "memory")

__device__ __forceinline__ void cp16(const void* g, void* l) {
  __builtin_amdgcn_global_load_lds((glb_u32*)g, (lds_u32*)l, 16, 0, 0);
}

__device__ __forceinline__ float fexp2(float x) {  // raw v_exp_f32
  return __builtin_amdgcn_exp2f(x);
}

__device__ __forceinline__ unsigned pk2(float a, float b) {
  __hip_bfloat16 ha = __float2bfloat16(a), hb = __float2bfloat16(b);
  return ((unsigned)__builtin_bit_cast(unsigned short, hb) << 16) |
         (unsigned)__builtin_bit_cast(unsigned short, ha);
}

__device__ __forceinline__ unsigned pku(__hip_bfloat16 lo, __hip_bfloat16 hi) {
  return ((unsigned)__builtin_bit_cast(unsigned short, hi) << 16) |
         (unsigned)__builtin_bit_cast(unsigned short, lo);
}

// Fragment-order global layouts (16x16 frags, 1024 B = 512 bf16 each):
//   qfb/kfb: [b][tile(32)][frag(4)][lane][8]   frag = row-16-group within tile
//   vfb:     [b][tile(32)][kc*2+vs][lane][8]   col v=vs*16+l15, t=kc*32+lg*8..
//   whT:     [dt(4)][lane][8]                  col d=dt*16+l15, k: v=lg*8..

// ---------------- Kernel 0: pack weights once (1 block) ----------------
__global__ __launch_bounds__(256) void prep_kernel(
    const float* __restrict__ Wq, const float* __restrict__ Wk,
    const float* __restrict__ Wv, const float* __restrict__ Wh,
    __hip_bfloat16* __restrict__ wt, __hip_bfloat16* __restrict__ whT) {
  const int tid = threadIdx.x;
  for (int o = tid; o < 6144; o += 256) {
    const int n = o / 72, d = o % 72;
    float val = 0.f;
    if (o < 5760 && d < ND) {
      if (n < 24)      val = Wq[d * NDK + n] * LOG2E;
      else if (n < 48) val = Wk[d * NDK + (n - 24)];
      else             val = Wv[d * NDV + (n - 48)];
    }
    wt[o] = __float2bfloat16(val);
  }
  {
    const int lane = tid & 63, l15 = lane & 15, lg = lane >> 4;
    const int d = (tid >> 6) * 16 + l15;
    uint4 u;
    u.x = pk2(Wh[(lg * 8 + 0) * ND + d], Wh[(lg * 8 + 1) * ND + d]);
    u.y = pk2(Wh[(lg * 8 + 2) * ND + d], Wh[(lg * 8 + 3) * ND + d]);
    u.z = pk2(Wh[(lg * 8 + 4) * ND + d], Wh[(lg * 8 + 5) * ND + d]);
    u.w = pk2(Wh[(lg * 8 + 6) * ND + d], Wh[(lg * 8 + 7) * ND + d]);
    ((uint4*)whT)[tid] = u;
  }
}

// ---------------- Kernel 1: projections via MFMA, fragment-order outputs ----
__global__ __launch_bounds__(256) void proj_kernel(
    const float* __restrict__ x, const __hip_bfloat16* __restrict__ wt,
    __hip_bfloat16* __restrict__ qfb, __hip_bfloat16* __restrict__ kfb,
    __hip_bfloat16* __restrict__ vfb) {
  __shared__ __hip_bfloat16 xsb[64 * 72];
  __shared__ __hip_bfloat16 Wt[6144];
  __shared__ __hip_bfloat16 os[64][81];

  const int tid = threadIdx.x;
  const size_t row0 = (size_t)blockIdx.x * 64;
  const int b = (int)(row0 >> 11);
  const int tile = (int)((row0 >> 6) & 31);
  const int wv = tid >> 6, lane = tid & 63;
  const int l15 = lane & 15, lg = lane >> 4;

  #pragma unroll
  for (int i = 0; i < 3; ++i)
    cp16((const char*)wt + (i * 256 + tid) * 16, (char*)Wt + (i * 256 + tid) * 16);

  {
    const int r = tid >> 2, c16 = (tid & 3) * 16;
    const float4* src = (const float4*)(x + (row0 + r) * ND + c16);
    unsigned u[8];
    #pragma unroll
    for (int i = 0; i < 4; ++i) {
      float4 f = src[i];
      u[2 * i] = pk2(f.x, f.y);
      u[2 * i + 1] = pk2(f.z, f.w);
    }
    uint4* dst = (uint4*)((char*)xsb + r * 144 + c16 * 2);
    dst[0] = make_uint4(u[0], u[1], u[2], u[3]);
    dst[1] = make_uint4(u[4], u[5], u[6], u[7]);
  }
  __syncthreads();

  {
    short8 a[2];
    #pragma unroll
    for (int kc = 0; kc < 2; ++kc)
      a[kc] = *(const short8*)((char*)xsb + ((wv * 16 + l15) * 72 + kc * 32 + lg * 8) * 2);
    const f32x4 z = {0.f, 0.f, 0.f, 0.f};
    #pragma unroll
    for (int nt = 0; nt < 5; ++nt) {
      f32x4 acc = z;
      #pragma unroll
      for (int kc = 0; kc < 2; ++kc) {
        const short8 bfr = *(const short8*)((char*)Wt + ((nt * 16 + l15) * 72 + kc * 32 + lg * 8) * 2);
        acc = __builtin_amdgcn_mfma_f32_16x16x32_bf16(a[kc], bfr, acc, 0, 0, 0);
      }
      #pragma unroll
      for (int r = 0; r < 4; ++r)
        os[wv * 16 + lg * 4 + r][nt * 16 + l15] = __float2bfloat16(acc[r]);
    }
  }
  __syncthreads();

  const size_t fbase = ((size_t)(b * 32 + tile)) * 4 * 256;  // in u32 units
  for (int j = tid; j < 2048; j += 256) {
    const int arr = j >> 10, jj = j & 1023;
    const int qs = jj >> 8, ln = (jj >> 2) & 63, wd = jj & 3;
    const int row = qs * 16 + (ln & 15);
    const int c0 = (ln >> 4) * 8 + wd * 2;
    unsigned u = 0;
    if (c0 < 24) u = pku(os[row][arr * 24 + c0], os[row][arr * 24 + c0 + 1]);
    unsigned* dst = (unsigned*)(arr ? kfb : qfb);
    dst[fbase + (size_t)qs * 256 + ln * 4 + wd] = u;
  }
  for (int j = tid; j < 1024; j += 256) {
    const int fi = j >> 8;                  // kc*2+vs
    const int ln = (j >> 2) & 63, wd = j & 3;
    const int v = (fi & 1) * 16 + (ln & 15);
    const int tl = (fi >> 1) * 32 + (ln >> 4) * 8 + wd * 2;
    const unsigned u = pku(os[tl][48 + v], os[tl + 1][48 + v]);
    ((unsigned*)vfb)[fbase + (size_t)fi * 256 + ln * 4 + wd] = u;
  }
}

// ---------------- Kernel 2: stats — 1-wave blocks (grid 2048), 2 t-frag/wave -
struct QT { short8 q0, q1, q2, q3; };

__device__ __forceinline__ void loadQ(QT& t, const __hip_bfloat16* qp, int it, int lane) {
  const __hip_bfloat16* p = qp + (size_t)it * 2048 + lane * 8;
  t.q0 = *(const short8*)(p);
  t.q1 = *(const short8*)(p + 512);
  t.q2 = *(const short8*)(p + 1024);
  t.q3 = *(const short8*)(p + 1536);
}

__device__ __forceinline__ void accQ(const QT& t, short8 kf0, short8 kf1,
                                     f32x4& s0, f32x4& s1) {
  const f32x4 z = {0.f, 0.f, 0.f, 0.f};
  #pragma unroll
  for (int qi = 0; qi < 4; ++qi) {
    const short8 q = qi == 0 ? t.q0 : qi == 1 ? t.q1 : qi == 2 ? t.q2 : t.q3;
    f32x4 d0 = __builtin_amdgcn_mfma_f32_16x16x32_bf16(kf0, q, z, 0, 0, 0);
    f32x4 d1 = __builtin_amdgcn_mfma_f32_16x16x32_bf16(kf1, q, z, 0, 0, 0);
    #pragma unroll
    for (int r = 0; r < 4; ++r) { s0[r] += fexp2(d0[r]); s1[r] += fexp2(d1[r]); }
  }
}

__global__ __launch_bounds__(64) void stats_kernel(
    const __hip_bfloat16* __restrict__ qfb, const __hip_bfloat16* __restrict__ kfb,
    float* __restrict__ ls) {
  const int g = blockIdx.x;
  const int xcd = g & 7, loc = g >> 3;      // 2048 = 8 xcd * 256
  const int b = (xcd << 2) + (loc >> 6);
  const int unit = loc & 63;                // wave-unit: 2 t-frags (32 t)
  const int lane = threadIdx.x;
  const int l15 = lane & 15, lg = lane >> 4;
  const int tile_t = unit >> 1;
  const int ib = (unit & 1) * 2;

  short8 kf[2];
  #pragma unroll
  for (int j = 0; j < 2; ++j)
    kf[j] = *(const short8*)(kfb + (((size_t)(b * 32 + tile_t)) * 4 + ib + j) * 512 + lane * 8);

  const __hip_bfloat16* qp = qfb + (size_t)b * 32 * 2048;
  const f32x4 z = {0.f, 0.f, 0.f, 0.f};
  f32x4 s0 = z, s1 = z;

  QT A, B;
  loadQ(A, qp, 0, lane);
  for (int it2 = 0; it2 < 16; ++it2) {
    const int itA = it2 * 2;
    loadQ(B, qp, itA + 1, lane);
    accQ(A, kf[0], kf[1], s0, s1);
    loadQ(A, qp, itA + 2 < 32 ? itA + 2 : 31, lane);
    accQ(B, kf[0], kf[1], s0, s1);
  }
  #pragma unroll
  for (int m = 1; m < 16; m <<= 1) {
    #pragma unroll
    for (int r = 0; r < 4; ++r) {
      s0[r] += __shfl_xor(s0[r], m);
      s1[r] += __shfl_xor(s1[r], m);
    }
  }
  if (l15 == 0) {
    f32x4 o0, o1;
    #pragma unroll
    for (int r = 0; r < 4; ++r) { o0[r] = -__log2f(s0[r]); o1[r] = -__log2f(s1[r]); }
    float* lp = ls + ((size_t)b << 11) + tile_t * 64 + ib * 16 + lg * 4;
    *(f32x4*)(lp) = o0;
    *(f32x4*)(lp + 16) = o1;
  }
}

// ---------------- Kernel 3: attn — 1-wave blocks (grid 2048), 2 q-frag/wave --
struct KVT {
  short8 k0, k1, k2, k3;
  short8 v0, v1, v2, v3;
  f32x4 l0, l1, l2, l3;
};

__device__ __forceinline__ void loadKV(KVT& t, const __hip_bfloat16* kp0,
    const __hip_bfloat16* vp0, const float* lsb, int it, int lane, int lg) {
  const __hip_bfloat16* kp = kp0 + (size_t)it * 2048 + lane * 8;
  t.k0 = *(const short8*)(kp);
  t.k1 = *(const short8*)(kp + 512);
  t.k2 = *(const short8*)(kp + 1024);
  t.k3 = *(const short8*)(kp + 1536);
  const __hip_bfloat16* vp = vp0 + (size_t)it * 2048 + lane * 8;
  t.v0 = *(const short8*)(vp);
  t.v1 = *(const short8*)(vp + 512);
  t.v2 = *(const short8*)(vp + 1024);
  t.v3 = *(const short8*)(vp + 1536);
  const float* lp = lsb + it * 64 + lg * 4;
  t.l0 = *(const f32x4*)(lp);
  t.l1 = *(const f32x4*)(lp + 16);
  t.l2 = *(const f32x4*)(lp + 32);
  t.l3 = *(const f32x4*)(lp + 48);
}

// per-wave P region: 16 rows (q) x 176 B
__device__ __forceinline__ void computeKV(const KVT& t, short8 qf, char* Pw,
                                          int lg, f32x4& h10, f32x4& h11) {
  f32x4 d;
  uint2 w;
  d = __builtin_amdgcn_mfma_f32_16x16x32_bf16(t.k0, qf, t.l0, 0, 0, 0);
  w.x = pk2(fexp2(d[0]), fexp2(d[1]));
  w.y = pk2(fexp2(d[2]), fexp2(d[3]));
  *(uint2*)(Pw + lg * 8) = w;
  d = __builtin_amdgcn_mfma_f32_16x16x32_bf16(t.k1, qf, t.l1, 0, 0, 0);
  w.x = pk2(fexp2(d[0]), fexp2(d[1]));
  w.y = pk2(fexp2(d[2]), fexp2(d[3]));
  *(uint2*)(Pw + 32 + lg * 8) = w;
  d = __builtin_amdgcn_mfma_f32_16x16x32_bf16(t.k2, qf, t.l2, 0, 0, 0);
  w.x = pk2(fexp2(d[0]), fexp2(d[1]));
  w.y = pk2(fexp2(d[2]), fexp2(d[3]));
  *(uint2*)(Pw + 64 + lg * 8) = w;
  d = __builtin_amdgcn_mfma_f32_16x16x32_bf16(t.k3, qf, t.l3, 0, 0, 0);
  w.x = pk2(fexp2(d[0]), fexp2(d[1]));
  w.y = pk2(fexp2(d[2]), fexp2(d[3]));
  *(uint2*)(Pw + 96 + lg * 8) = w;
  LFENCE;  // pin P ds_write -> ds_read order (same wave, in-order DS pipe)
  const short8 p0 = *(const short8*)(Pw + lg * 16);
  const short8 p1 = *(const short8*)(Pw + 64 + lg * 16);
  h10 = __builtin_amdgcn_mfma_f32_16x16x32_bf16(p0, t.v0, h10, 0, 0, 0);
  h11 = __builtin_amdgcn_mfma_f32_16x16x32_bf16(p0, t.v1, h11, 0, 0, 0);
  h10 = __builtin_amdgcn_mfma_f32_16x16x32_bf16(p1, t.v2, h10, 0, 0, 0);
  h11 = __builtin_amdgcn_mfma_f32_16x16x32_bf16(p1, t.v3, h11, 0, 0, 0);
  LFENCE;  // keep next block's P writes after these reads
}

__global__ __launch_bounds__(64) void attn_kernel(
    const __hip_bfloat16* __restrict__ qfb, const __hip_bfloat16* __restrict__ kfb,
    const __hip_bfloat16* __restrict__ vfb, const float* __restrict__ ls,
    const __hip_bfloat16* __restrict__ whT, float* __restrict__ out) {
  __shared__ char Ps[2816];   // 1 wave x 16 rows x 176 B

  const int g = blockIdx.x;
  const int xcd = g & 7, loc = g >> 3;      // 2048 = 8 xcd * 256
  const int b = (xcd << 2) + (loc >> 6);
  const int unit = loc & 63;                // wave-unit: 2 q-frags (32 q)
  const int lane = threadIdx.x;
  const int l15 = lane & 15, lg = lane >> 4;
  const int tile_q = unit >> 1;
  const int ib = (unit & 1) * 2;

  char* Pw = Ps + l15 * 176;

  short8 qf[2];
  #pragma unroll
  for (int qi = 0; qi < 2; ++qi)
    qf[qi] = *(const short8*)(qfb + (((size_t)(b * 32 + tile_q)) * 4 + ib + qi) * 512 + lane * 8);

  const __hip_bfloat16* kp0 = kfb + (size_t)b * 32 * 2048;
  const __hip_bfloat16* vp0 = vfb + (size_t)b * 32 * 2048;
  const float* lsb = ls + ((size_t)b << 11);

  const f32x4 z = {0.f, 0.f, 0.f, 0.f};
  f32x4 h1[2][2] = {{z, z}, {z, z}};

  KVT A, B;
  loadKV(A, kp0, vp0, lsb, 0, lane, lg);
  for (int it2 = 0; it2 < 16; ++it2) {
    const int itA = it2 * 2;
    loadKV(B, kp0, vp0, lsb, itA + 1, lane, lg);
    computeKV(A, qf[0], Pw, lg, h1[0][0], h1[0][1]);
    computeKV(A, qf[1], Pw, lg, h1[1][0], h1[1][1]);
    loadKV(A, kp0, vp0, lsb, itA + 2 < 32 ? itA + 2 : 31, lane, lg);
    computeKV(B, qf[0], Pw, lg, h1[0][0], h1[0][1]);
    computeKV(B, qf[1], Pw, lg, h1[1][0], h1[1][1]);
  }

  // epilogue: out = h1 @ Wh per q-frag (single wave, no barrier needed)
  short8 wf[4];
  #pragma unroll
  for (int dt = 0; dt < 4; ++dt)
    wf[dt] = *(const short8*)(whT + dt * 512 + lane * 8);
  #pragma unroll
  for (int qi = 0; qi < 2; ++qi) {
    #pragma unroll
    for (int vs = 0; vs < 2; ++vs)
      #pragma unroll
      for (int r = 0; r < 4; ++r)
        *(unsigned short*)(Ps + (lg * 4 + r) * 176 + (vs * 16 + l15) * 2) =
            __builtin_bit_cast(unsigned short, __float2bfloat16(h1[qi][vs][r]));
    LFENCE;
    const short8 hf = *(const short8*)(Pw + lg * 16);
    float* ob = out + (size_t)(b * NS + tile_q * 64 + (ib + qi) * 16 + lg * 4) * ND + l15;
    #pragma unroll
    for (int dt = 0; dt < 4; ++dt) {
      f32x4 o = __builtin_amdgcn_mfma_f32_16x16x32_bf16(hf, wf[dt], z, 0, 0, 0);
      float* op = ob + dt * 16;
      op[0] = o[0];
      op[ND] = o[1];
      op[2 * ND] = o[2];
      op[3 * ND] = o[3];
    }
    LFENCE;
  }
}

// ---------------- launcher ----------------
extern "C" void kernel_launch(void* const* d_in, const int* in_sizes, int n_in,
                              void* d_out, int out_size, void* d_ws, size_t ws_size,
                              hipStream_t stream) {
  const float* x  = (const float*)d_in[0];
  const float* Wq = (const float*)d_in[1];
  const float* Wk = (const float*)d_in[2];
  const float* Wv = (const float*)d_in[3];
  const float* Wh = (const float*)d_in[4];
  float* out = (float*)d_out;

  char* ws = (char*)d_ws;
  __hip_bfloat16* qfb = (__hip_bfloat16*)ws;                   // 4 MB
  __hip_bfloat16* kfb = (__hip_bfloat16*)(ws + 4194304);       // 4 MB
  __hip_bfloat16* vfb = (__hip_bfloat16*)(ws + 8388608);       // 4 MB
  float*          lsp = (float*)(ws + 12582912);               // 256 KB
  __hip_bfloat16* whT = (__hip_bfloat16*)(ws + 12845056);      // 4 KB
  __hip_bfloat16* wt  = (__hip_bfloat16*)(ws + 12849152);      // 12 KB

  hipLaunchKernelGGL(prep_kernel, dim3(1), dim3(256), 0, stream,
                     Wq, Wk, Wv, Wh, wt, whT);
  hipLaunchKernelGGL(proj_kernel, dim3(1024), dim3(256), 0, stream,
                     x, wt, qfb, kfb, vfb);
  hipLaunchKernelGGL(stats_kernel, dim3(2048), dim3(64), 0, stream,
                     qfb, kfb, lsp);
  hipLaunchKernelGGL(attn_kernel, dim3(2048), dim3(64), 0, stream,
                     qfb, kfb, vfb, lsp, whT, out);
}

// Round 22
// 72.604 us; speedup vs baseline: 1.1075x; 1.0657x over previous
//
#include <hip/hip_runtime.h>
#include <hip/hip_bf16.h>

#define NB 32
#define NS 2048
#define ND 64
#define NDK 24
#define NDV 32
#define LOG2E 1.4426950408889634f

typedef __attribute__((ext_vector_type(8))) short short8;
typedef __attribute__((ext_vector_type(4))) float f32x4;

typedef __attribute__((address_space(3))) unsigned int lds_u32;
typedef __attribute__((address_space(1))) const unsigned int glb_u32;

#define LFENCE asm volatile("" ::: "memory")
// scheduling wall: pin prefetch-load ISSUE here (prevents the scheduler from
// sinking the global loads down to their use, which voids the ping-pong)
#define SCHEDW __builtin_amdgcn_sched_barrier(0)

__device__ __forceinline__ void cp16(const void* g, void* l) {
  __builtin_amdgcn_global_load_lds((glb_u32*)g, (lds_u32*)l, 16, 0, 0);
}

__device__ __forceinline__ float fexp2(float x) {  // raw v_exp_f32
  return __builtin_amdgcn_exp2f(x);
}

__device__ __forceinline__ unsigned pk2(float a, float b) {
  __hip_bfloat16 ha = __float2bfloat16(a), hb = __float2bfloat16(b);
  return ((unsigned)__builtin_bit_cast(unsigned short, hb) << 16) |
         (unsigned)__builtin_bit_cast(unsigned short, ha);
}

__device__ __forceinline__ unsigned pku(__hip_bfloat16 lo, __hip_bfloat16 hi) {
  return ((unsigned)__builtin_bit_cast(unsigned short, hi) << 16) |
         (unsigned)__builtin_bit_cast(unsigned short, lo);
}

// Fragment-order global layouts (16x16 frags, 1024 B = 512 bf16 each):
//   qfb/kfb: [b][tile(32)][frag(4)][lane][8]   frag = row-16-group within tile
//   vfb:     [b][tile(32)][kc*2+vs][lane][8]   col v=vs*16+l15, t=kc*32+lg*8..
//   whT:     [dt(4)][lane][8]                  col d=dt*16+l15, k: v=lg*8..

// ---------------- Kernel 0: pack weights once (1 block) ----------------
__global__ __launch_bounds__(256) void prep_kernel(
    const float* __restrict__ Wq, const float* __restrict__ Wk,
    const float* __restrict__ Wv, const float* __restrict__ Wh,
    __hip_bfloat16* __restrict__ wt, __hip_bfloat16* __restrict__ whT) {
  const int tid = threadIdx.x;
  for (int o = tid; o < 6144; o += 256) {
    const int n = o / 72, d = o % 72;
    float val = 0.f;
    if (o < 5760 && d < ND) {
      if (n < 24)      val = Wq[d * NDK + n] * LOG2E;
      else if (n < 48) val = Wk[d * NDK + (n - 24)];
      else             val = Wv[d * NDV + (n - 48)];
    }
    wt[o] = __float2bfloat16(val);
  }
  {
    const int lane = tid & 63, l15 = lane & 15, lg = lane >> 4;
    const int d = (tid >> 6) * 16 + l15;
    uint4 u;
    u.x = pk2(Wh[(lg * 8 + 0) * ND + d], Wh[(lg * 8 + 1) * ND + d]);
    u.y = pk2(Wh[(lg * 8 + 2) * ND + d], Wh[(lg * 8 + 3) * ND + d]);
    u.z = pk2(Wh[(lg * 8 + 4) * ND + d], Wh[(lg * 8 + 5) * ND + d]);
    u.w = pk2(Wh[(lg * 8 + 6) * ND + d], Wh[(lg * 8 + 7) * ND + d]);
    ((uint4*)whT)[tid] = u;
  }
}

// ---------------- Kernel 1: projections via MFMA, fragment-order outputs ----
__global__ __launch_bounds__(256) void proj_kernel(
    const float* __restrict__ x, const __hip_bfloat16* __restrict__ wt,
    __hip_bfloat16* __restrict__ qfb, __hip_bfloat16* __restrict__ kfb,
    __hip_bfloat16* __restrict__ vfb) {
  __shared__ __hip_bfloat16 xsb[64 * 72];
  __shared__ __hip_bfloat16 Wt[6144];
  __shared__ __hip_bfloat16 os[64][81];

  const int tid = threadIdx.x;
  const size_t row0 = (size_t)blockIdx.x * 64;
  const int b = (int)(row0 >> 11);
  const int tile = (int)((row0 >> 6) & 31);
  const int wv = tid >> 6, lane = tid & 63;
  const int l15 = lane & 15, lg = lane >> 4;

  #pragma unroll
  for (int i = 0; i < 3; ++i)
    cp16((const char*)wt + (i * 256 + tid) * 16, (char*)Wt + (i * 256 + tid) * 16);

  {
    const int r = tid >> 2, c16 = (tid & 3) * 16;
    const float4* src = (const float4*)(x + (row0 + r) * ND + c16);
    unsigned u[8];
    #pragma unroll
    for (int i = 0; i < 4; ++i) {
      float4 f = src[i];
      u[2 * i] = pk2(f.x, f.y);
      u[2 * i + 1] = pk2(f.z, f.w);
    }
    uint4* dst = (uint4*)((char*)xsb + r * 144 + c16 * 2);
    dst[0] = make_uint4(u[0], u[1], u[2], u[3]);
    dst[1] = make_uint4(u[4], u[5], u[6], u[7]);
  }
  __syncthreads();

  {
    short8 a[2];
    #pragma unroll
    for (int kc = 0; kc < 2; ++kc)
      a[kc] = *(const short8*)((char*)xsb + ((wv * 16 + l15) * 72 + kc * 32 + lg * 8) * 2);
    const f32x4 z = {0.f, 0.f, 0.f, 0.f};
    #pragma unroll
    for (int nt = 0; nt < 5; ++nt) {
      f32x4 acc = z;
      #pragma unroll
      for (int kc = 0; kc < 2; ++kc) {
        const short8 bfr = *(const short8*)((char*)Wt + ((nt * 16 + l15) * 72 + kc * 32 + lg * 8) * 2);
        acc = __builtin_amdgcn_mfma_f32_16x16x32_bf16(a[kc], bfr, acc, 0, 0, 0);
      }
      #pragma unroll
      for (int r = 0; r < 4; ++r)
        os[wv * 16 + lg * 4 + r][nt * 16 + l15] = __float2bfloat16(acc[r]);
    }
  }
  __syncthreads();

  const size_t fbase = ((size_t)(b * 32 + tile)) * 4 * 256;  // in u32 units
  for (int j = tid; j < 2048; j += 256) {
    const int arr = j >> 10, jj = j & 1023;
    const int qs = jj >> 8, ln = (jj >> 2) & 63, wd = jj & 3;
    const int row = qs * 16 + (ln & 15);
    const int c0 = (ln >> 4) * 8 + wd * 2;
    unsigned u = 0;
    if (c0 < 24) u = pku(os[row][arr * 24 + c0], os[row][arr * 24 + c0 + 1]);
    unsigned* dst = (unsigned*)(arr ? kfb : qfb);
    dst[fbase + (size_t)qs * 256 + ln * 4 + wd] = u;
  }
  for (int j = tid; j < 1024; j += 256) {
    const int fi = j >> 8;                  // kc*2+vs
    const int ln = (j >> 2) & 63, wd = j & 3;
    const int v = (fi & 1) * 16 + (ln & 15);
    const int tl = (fi >> 1) * 32 + (ln >> 4) * 8 + wd * 2;
    const unsigned u = pku(os[tl][48 + v], os[tl + 1][48 + v]);
    ((unsigned*)vfb)[fbase + (size_t)fi * 256 + ln * 4 + wd] = u;
  }
}

// ---------------- Kernel 2: stats — 1-wave blocks, pinned prefetch ----------
struct QT { short8 q0, q1, q2, q3; };

__device__ __forceinline__ void loadQ(QT& t, const __hip_bfloat16* qp, int it, int lane) {
  const __hip_bfloat16* p = qp + (size_t)it * 2048 + lane * 8;
  t.q0 = *(const short8*)(p);
  t.q1 = *(const short8*)(p + 512);
  t.q2 = *(const short8*)(p + 1024);
  t.q3 = *(const short8*)(p + 1536);
}

__device__ __forceinline__ void accQ(const QT& t, short8 kf0, short8 kf1,
                                     f32x4& s0, f32x4& s1) {
  const f32x4 z = {0.f, 0.f, 0.f, 0.f};
  #pragma unroll
  for (int qi = 0; qi < 4; ++qi) {
    const short8 q = qi == 0 ? t.q0 : qi == 1 ? t.q1 : qi == 2 ? t.q2 : t.q3;
    f32x4 d0 = __builtin_amdgcn_mfma_f32_16x16x32_bf16(kf0, q, z, 0, 0, 0);
    f32x4 d1 = __builtin_amdgcn_mfma_f32_16x16x32_bf16(kf1, q, z, 0, 0, 0);
    #pragma unroll
    for (int r = 0; r < 4; ++r) { s0[r] += fexp2(d0[r]); s1[r] += fexp2(d1[r]); }
  }
}

__global__ __launch_bounds__(64) void stats_kernel(
    const __hip_bfloat16* __restrict__ qfb, const __hip_bfloat16* __restrict__ kfb,
    float* __restrict__ ls) {
  const int g = blockIdx.x;
  const int xcd = g & 7, loc = g >> 3;      // 2048 = 8 xcd * 256
  const int b = (xcd << 2) + (loc >> 6);
  const int unit = loc & 63;                // wave-unit: 2 t-frags (32 t)
  const int lane = threadIdx.x;
  const int l15 = lane & 15, lg = lane >> 4;
  const int tile_t = unit >> 1;
  const int ib = (unit & 1) * 2;

  short8 kf[2];
  #pragma unroll
  for (int j = 0; j < 2; ++j)
    kf[j] = *(const short8*)(kfb + (((size_t)(b * 32 + tile_t)) * 4 + ib + j) * 512 + lane * 8);

  const __hip_bfloat16* qp = qfb + (size_t)b * 32 * 2048;
  const f32x4 z = {0.f, 0.f, 0.f, 0.f};
  f32x4 s0 = z, s1 = z;

  QT A, B;
  loadQ(A, qp, 0, lane);
  for (int it2 = 0; it2 < 16; ++it2) {
    const int itA = it2 * 2;
    loadQ(B, qp, itA + 1, lane);
    SCHEDW;                         // pin B's loads: issue HERE, wait at use
    accQ(A, kf[0], kf[1], s0, s1);
    loadQ(A, qp, itA + 2 < 32 ? itA + 2 : 31, lane);
    SCHEDW;
    accQ(B, kf[0], kf[1], s0, s1);
  }
  #pragma unroll
  for (int m = 1; m < 16; m <<= 1) {
    #pragma unroll
    for (int r = 0; r < 4; ++r) {
      s0[r] += __shfl_xor(s0[r], m);
      s1[r] += __shfl_xor(s1[r], m);
    }
  }
  if (l15 == 0) {
    f32x4 o0, o1;
    #pragma unroll
    for (int r = 0; r < 4; ++r) { o0[r] = -__log2f(s0[r]); o1[r] = -__log2f(s1[r]); }
    float* lp = ls + ((size_t)b << 11) + tile_t * 64 + ib * 16 + lg * 4;
    *(f32x4*)(lp) = o0;
    *(f32x4*)(lp + 16) = o1;
  }
}

// ---------------- Kernel 3: attn — 1-wave blocks, pinned prefetch -----------
struct KVT {
  short8 k0, k1, k2, k3;
  short8 v0, v1, v2, v3;
  f32x4 l0, l1, l2, l3;
};

__device__ __forceinline__ void loadKV(KVT& t, const __hip_bfloat16* kp0,
    const __hip_bfloat16* vp0, const float* lsb, int it, int lane, int lg) {
  const __hip_bfloat16* kp = kp0 + (size_t)it * 2048 + lane * 8;
  t.k0 = *(const short8*)(kp);
  t.k1 = *(const short8*)(kp + 512);
  t.k2 = *(const short8*)(kp + 1024);
  t.k3 = *(const short8*)(kp + 1536);
  const __hip_bfloat16* vp = vp0 + (size_t)it * 2048 + lane * 8;
  t.v0 = *(const short8*)(vp);
  t.v1 = *(const short8*)(vp + 512);
  t.v2 = *(const short8*)(vp + 1024);
  t.v3 = *(const short8*)(vp + 1536);
  const float* lp = lsb + it * 64 + lg * 4;
  t.l0 = *(const f32x4*)(lp);
  t.l1 = *(const f32x4*)(lp + 16);
  t.l2 = *(const f32x4*)(lp + 32);
  t.l3 = *(const f32x4*)(lp + 48);
}

// per-wave P region: 16 rows (q) x 176 B
__device__ __forceinline__ void computeKV(const KVT& t, short8 qf, char* Pw,
                                          int lg, f32x4& h10, f32x4& h11) {
  f32x4 d;
  uint2 w;
  d = __builtin_amdgcn_mfma_f32_16x16x32_bf16(t.k0, qf, t.l0, 0, 0, 0);
  w.x = pk2(fexp2(d[0]), fexp2(d[1]));
  w.y = pk2(fexp2(d[2]), fexp2(d[3]));
  *(uint2*)(Pw + lg * 8) = w;
  d = __builtin_amdgcn_mfma_f32_16x16x32_bf16(t.k1, qf, t.l1, 0, 0, 0);
  w.x = pk2(fexp2(d[0]), fexp2(d[1]));
  w.y = pk2(fexp2(d[2]), fexp2(d[3]));
  *(uint2*)(Pw + 32 + lg * 8) = w;
  d = __builtin_amdgcn_mfma_f32_16x16x32_bf16(t.k2, qf, t.l2, 0, 0, 0);
  w.x = pk2(fexp2(d[0]), fexp2(d[1]));
  w.y = pk2(fexp2(d[2]), fexp2(d[3]));
  *(uint2*)(Pw + 64 + lg * 8) = w;
  d = __builtin_amdgcn_mfma_f32_16x16x32_bf16(t.k3, qf, t.l3, 0, 0, 0);
  w.x = pk2(fexp2(d[0]), fexp2(d[1]));
  w.y = pk2(fexp2(d[2]), fexp2(d[3]));
  *(uint2*)(Pw + 96 + lg * 8) = w;
  LFENCE;  // pin P ds_write -> ds_read order (same wave, in-order DS pipe)
  const short8 p0 = *(const short8*)(Pw + lg * 16);
  const short8 p1 = *(const short8*)(Pw + 64 + lg * 16);
  h10 = __builtin_amdgcn_mfma_f32_16x16x32_bf16(p0, t.v0, h10, 0, 0, 0);
  h11 = __builtin_amdgcn_mfma_f32_16x16x32_bf16(p0, t.v1, h11, 0, 0, 0);
  h10 = __builtin_amdgcn_mfma_f32_16x16x32_bf16(p1, t.v2, h10, 0, 0, 0);
  h11 = __builtin_amdgcn_mfma_f32_16x16x32_bf16(p1, t.v3, h11, 0, 0, 0);
  LFENCE;  // keep next block's P writes after these reads
}

__global__ __launch_bounds__(64) void attn_kernel(
    const __hip_bfloat16* __restrict__ qfb, const __hip_bfloat16* __restrict__ kfb,
    const __hip_bfloat16* __restrict__ vfb, const float* __restrict__ ls,
    const __hip_bfloat16* __restrict__ whT, float* __restrict__ out) {
  __shared__ char Ps[2816];   // 1 wave x 16 rows x 176 B

  const int g = blockIdx.x;
  const int xcd = g & 7, loc = g >> 3;      // 2048 = 8 xcd * 256
  const int b = (xcd << 2) + (loc >> 6);
  const int unit = loc & 63;                // wave-unit: 2 q-frags (32 q)
  const int lane = threadIdx.x;
  const int l15 = lane & 15, lg = lane >> 4;
  const int tile_q = unit >> 1;
  const int ib = (unit & 1) * 2;

  char* Pw = Ps + l15 * 176;

  short8 qf[2];
  #pragma unroll
  for (int qi = 0; qi < 2; ++qi)
    qf[qi] = *(const short8*)(qfb + (((size_t)(b * 32 + tile_q)) * 4 + ib + qi) * 512 + lane * 8);

  const __hip_bfloat16* kp0 = kfb + (size_t)b * 32 * 2048;
  const __hip_bfloat16* vp0 = vfb + (size_t)b * 32 * 2048;
  const float* lsb = ls + ((size_t)b << 11);

  const f32x4 z = {0.f, 0.f, 0.f, 0.f};
  f32x4 h1[2][2] = {{z, z}, {z, z}};

  KVT A, B;
  loadKV(A, kp0, vp0, lsb, 0, lane, lg);
  SCHEDW;
  for (int it2 = 0; it2 < 16; ++it2) {
    const int itA = it2 * 2;
    loadKV(B, kp0, vp0, lsb, itA + 1, lane, lg);
    SCHEDW;                         // pin B's loads: issue HERE, wait at use
    computeKV(A, qf[0], Pw, lg, h1[0][0], h1[0][1]);
    computeKV(A, qf[1], Pw, lg, h1[1][0], h1[1][1]);
    loadKV(A, kp0, vp0, lsb, itA + 2 < 32 ? itA + 2 : 31, lane, lg);
    SCHEDW;                         // pin A's next-tile loads
    computeKV(B, qf[0], Pw, lg, h1[0][0], h1[0][1]);
    computeKV(B, qf[1], Pw, lg, h1[1][0], h1[1][1]);
  }

  // epilogue: out = h1 @ Wh per q-frag (single wave, no barrier needed)
  short8 wf[4];
  #pragma unroll
  for (int dt = 0; dt < 4; ++dt)
    wf[dt] = *(const short8*)(whT + dt * 512 + lane * 8);
  #pragma unroll
  for (int qi = 0; qi < 2; ++qi) {
    #pragma unroll
    for (int vs = 0; vs < 2; ++vs)
      #pragma unroll
      for (int r = 0; r < 4; ++r)
        *(unsigned short*)(Ps + (lg * 4 + r) * 176 + (vs * 16 + l15) * 2) =
            __builtin_bit_cast(unsigned short, __float2bfloat16(h1[qi][vs][r]));
    LFENCE;
    const short8 hf = *(const short8*)(Pw + lg * 16);
    float* ob = out + (size_t)(b * NS + tile_q * 64 + (ib + qi) * 16 + lg * 4) * ND + l15;
    #pragma unroll
    for (int dt = 0; dt < 4; ++dt) {
      f32x4 o = __builtin_amdgcn_mfma_f32_16x16x32_bf16(hf, wf[dt], z, 0, 0, 0);
      float* op = ob + dt * 16;
      op[0] = o[0];
      op[ND] = o[1];
      op[2 * ND] = o[2];
      op[3 * ND] = o[3];
    }
    LFENCE;
  }
}

// ---------------- launcher ----------------
extern "C" void kernel_launch(void* const* d_in, const int* in_sizes, int n_in,
                              void* d_out, int out_size, void* d_ws, size_t ws_size,
                              hipStream_t stream) {
  const float* x  = (const float*)d_in[0];
  const float* Wq = (const float*)d_in[1];
  const float* Wk = (const float*)d_in[2];
  const float* Wv = (const float*)d_in[3];
  const float* Wh = (const float*)d_in[4];
  float* out = (float*)d_out;

  char* ws = (char*)d_ws;
  __hip_bfloat16* qfb = (__hip_bfloat16*)ws;                   // 4 MB
  __hip_bfloat16* kfb = (__hip_bfloat16*)(ws + 4194304);       // 4 MB
  __hip_bfloat16* vfb = (__hip_bfloat16*)(ws + 8388608);       // 4 MB
  float*          lsp = (float*)(ws + 12582912);               // 256 KB
  __hip_bfloat16* whT = (__hip_bfloat16*)(ws + 12845056);      // 4 KB
  __hip_bfloat16* wt  = (__hip_bfloat16*)(ws + 12849152);      // 12 KB

  hipLaunchKernelGGL(prep_kernel, dim3(1), dim3(256), 0, stream,
                     Wq, Wk, Wv, Wh, wt, whT);
  hipLaunchKernelGGL(proj_kernel, dim3(1024), dim3(256), 0, stream,
                     x, wt, qfb, kfb, vfb);
  hipLaunchKernelGGL(stats_kernel, dim3(2048), dim3(64), 0, stream,
                     qfb, kfb, lsp);
  hipLaunchKernelGGL(attn_kernel, dim3(2048), dim3(64), 0, stream,
                     qfb, kfb, vfb, lsp, whT, out);
}

// Round 23
// 71.908 us; speedup vs baseline: 1.1182x; 1.0097x over previous
//
#include <hip/hip_runtime.h>
#include <hip/hip_bf16.h>

#define NB 32
#define NS 2048
#define ND 64
#define NDK 24
#define NDV 32
#define LOG2E 1.4426950408889634f

typedef __attribute__((ext_vector_type(8))) short short8;
typedef __attribute__((ext_vector_type(4))) float f32x4;

typedef __attribute__((address_space(3))) unsigned int lds_u32;
typedef __attribute__((address_space(1))) const unsigned int glb_u32;

#define LFENCE asm volatile("" ::: "memory")
// scheduling wall: pin prefetch-load ISSUE here (prevents the scheduler from
// sinking the global loads down to their use, which voids the ping-pong)
#define SCHEDW __builtin_amdgcn_sched_barrier(0)

__device__ __forceinline__ void cp16(const void* g, void* l) {
  __builtin_amdgcn_global_load_lds((glb_u32*)g, (lds_u32*)l, 16, 0, 0);
}

__device__ __forceinline__ float fexp2(float x) {  // raw v_exp_f32
  return __builtin_amdgcn_exp2f(x);
}

__device__ __forceinline__ unsigned pk2(float a, float b) {
  __hip_bfloat16 ha = __float2bfloat16(a), hb = __float2bfloat16(b);
  return ((unsigned)__builtin_bit_cast(unsigned short, hb) << 16) |
         (unsigned)__builtin_bit_cast(unsigned short, ha);
}

__device__ __forceinline__ unsigned pku(__hip_bfloat16 lo, __hip_bfloat16 hi) {
  return ((unsigned)__builtin_bit_cast(unsigned short, hi) << 16) |
         (unsigned)__builtin_bit_cast(unsigned short, lo);
}

// Fragment-order global layouts (16x16 frags, 1024 B = 512 bf16 each):
//   qfb/kfb: [b][tile(32)][frag(4)][lane][8]   frag = row-16-group within tile
//   vfb:     [b][tile(32)][kc*2+vs][lane][8]   col v=vs*16+l15, t=kc*32+lg*8..
//   whT:     [dt(4)][lane][8]                  col d=dt*16+l15, k: v=lg*8..

// ---------------- Kernel 0: pack weights once (1 block) ----------------
__global__ __launch_bounds__(256) void prep_kernel(
    const float* __restrict__ Wq, const float* __restrict__ Wk,
    const float* __restrict__ Wv, const float* __restrict__ Wh,
    __hip_bfloat16* __restrict__ wt, __hip_bfloat16* __restrict__ whT) {
  const int tid = threadIdx.x;
  for (int o = tid; o < 6144; o += 256) {
    const int n = o / 72, d = o % 72;
    float val = 0.f;
    if (o < 5760 && d < ND) {
      if (n < 24)      val = Wq[d * NDK + n] * LOG2E;
      else if (n < 48) val = Wk[d * NDK + (n - 24)];
      else             val = Wv[d * NDV + (n - 48)];
    }
    wt[o] = __float2bfloat16(val);
  }
  {
    const int lane = tid & 63, l15 = lane & 15, lg = lane >> 4;
    const int d = (tid >> 6) * 16 + l15;
    uint4 u;
    u.x = pk2(Wh[(lg * 8 + 0) * ND + d], Wh[(lg * 8 + 1) * ND + d]);
    u.y = pk2(Wh[(lg * 8 + 2) * ND + d], Wh[(lg * 8 + 3) * ND + d]);
    u.z = pk2(Wh[(lg * 8 + 4) * ND + d], Wh[(lg * 8 + 5) * ND + d]);
    u.w = pk2(Wh[(lg * 8 + 6) * ND + d], Wh[(lg * 8 + 7) * ND + d]);
    ((uint4*)whT)[tid] = u;
  }
}

// ---------------- Kernel 1: projections via MFMA, fragment-order outputs ----
__global__ __launch_bounds__(256) void proj_kernel(
    const float* __restrict__ x, const __hip_bfloat16* __restrict__ wt,
    __hip_bfloat16* __restrict__ qfb, __hip_bfloat16* __restrict__ kfb,
    __hip_bfloat16* __restrict__ vfb) {
  __shared__ __hip_bfloat16 xsb[64 * 72];
  __shared__ __hip_bfloat16 Wt[6144];
  __shared__ __hip_bfloat16 os[64][81];

  const int tid = threadIdx.x;
  const size_t row0 = (size_t)blockIdx.x * 64;
  const int b = (int)(row0 >> 11);
  const int tile = (int)((row0 >> 6) & 31);
  const int wv = tid >> 6, lane = tid & 63;
  const int l15 = lane & 15, lg = lane >> 4;

  #pragma unroll
  for (int i = 0; i < 3; ++i)
    cp16((const char*)wt + (i * 256 + tid) * 16, (char*)Wt + (i * 256 + tid) * 16);

  {
    const int r = tid >> 2, c16 = (tid & 3) * 16;
    const float4* src = (const float4*)(x + (row0 + r) * ND + c16);
    unsigned u[8];
    #pragma unroll
    for (int i = 0; i < 4; ++i) {
      float4 f = src[i];
      u[2 * i] = pk2(f.x, f.y);
      u[2 * i + 1] = pk2(f.z, f.w);
    }
    uint4* dst = (uint4*)((char*)xsb + r * 144 + c16 * 2);
    dst[0] = make_uint4(u[0], u[1], u[2], u[3]);
    dst[1] = make_uint4(u[4], u[5], u[6], u[7]);
  }
  __syncthreads();

  {
    short8 a[2];
    #pragma unroll
    for (int kc = 0; kc < 2; ++kc)
      a[kc] = *(const short8*)((char*)xsb + ((wv * 16 + l15) * 72 + kc * 32 + lg * 8) * 2);
    const f32x4 z = {0.f, 0.f, 0.f, 0.f};
    #pragma unroll
    for (int nt = 0; nt < 5; ++nt) {
      f32x4 acc = z;
      #pragma unroll
      for (int kc = 0; kc < 2; ++kc) {
        const short8 bfr = *(const short8*)((char*)Wt + ((nt * 16 + l15) * 72 + kc * 32 + lg * 8) * 2);
        acc = __builtin_amdgcn_mfma_f32_16x16x32_bf16(a[kc], bfr, acc, 0, 0, 0);
      }
      #pragma unroll
      for (int r = 0; r < 4; ++r)
        os[wv * 16 + lg * 4 + r][nt * 16 + l15] = __float2bfloat16(acc[r]);
    }
  }
  __syncthreads();

  const size_t fbase = ((size_t)(b * 32 + tile)) * 4 * 256;  // in u32 units
  for (int j = tid; j < 2048; j += 256) {
    const int arr = j >> 10, jj = j & 1023;
    const int qs = jj >> 8, ln = (jj >> 2) & 63, wd = jj & 3;
    const int row = qs * 16 + (ln & 15);
    const int c0 = (ln >> 4) * 8 + wd * 2;
    unsigned u = 0;
    if (c0 < 24) u = pku(os[row][arr * 24 + c0], os[row][arr * 24 + c0 + 1]);
    unsigned* dst = (unsigned*)(arr ? kfb : qfb);
    dst[fbase + (size_t)qs * 256 + ln * 4 + wd] = u;
  }
  for (int j = tid; j < 1024; j += 256) {
    const int fi = j >> 8;                  // kc*2+vs
    const int ln = (j >> 2) & 63, wd = j & 3;
    const int v = (fi & 1) * 16 + (ln & 15);
    const int tl = (fi >> 1) * 32 + (ln >> 4) * 8 + wd * 2;
    const unsigned u = pku(os[tl][48 + v], os[tl + 1][48 + v]);
    ((unsigned*)vfb)[fbase + (size_t)fi * 256 + ln * 4 + wd] = u;
  }
}

// ---------------- Kernel 2: stats — 1-wave blocks, pinned prefetch ----------
struct QT { short8 q0, q1, q2, q3; };

__device__ __forceinline__ void loadQ(QT& t, const __hip_bfloat16* qp, int it, int lane) {
  const __hip_bfloat16* p = qp + (size_t)it * 2048 + lane * 8;
  t.q0 = *(const short8*)(p);
  t.q1 = *(const short8*)(p + 512);
  t.q2 = *(const short8*)(p + 1024);
  t.q3 = *(const short8*)(p + 1536);
}

__device__ __forceinline__ void accQ(const QT& t, short8 kf0, short8 kf1,
                                     f32x4& s0, f32x4& s1) {
  const f32x4 z = {0.f, 0.f, 0.f, 0.f};
  #pragma unroll
  for (int qi = 0; qi < 4; ++qi) {
    const short8 q = qi == 0 ? t.q0 : qi == 1 ? t.q1 : qi == 2 ? t.q2 : t.q3;
    f32x4 d0 = __builtin_amdgcn_mfma_f32_16x16x32_bf16(kf0, q, z, 0, 0, 0);
    f32x4 d1 = __builtin_amdgcn_mfma_f32_16x16x32_bf16(kf1, q, z, 0, 0, 0);
    #pragma unroll
    for (int r = 0; r < 4; ++r) { s0[r] += fexp2(d0[r]); s1[r] += fexp2(d1[r]); }
  }
}

__global__ __launch_bounds__(64) void stats_kernel(
    const __hip_bfloat16* __restrict__ qfb, const __hip_bfloat16* __restrict__ kfb,
    float* __restrict__ ls) {
  const int g = blockIdx.x;
  const int xcd = g & 7, loc = g >> 3;      // 2048 = 8 xcd * 256
  const int b = (xcd << 2) + (loc >> 6);
  const int unit = loc & 63;                // wave-unit: 2 t-frags (32 t)
  const int lane = threadIdx.x;
  const int l15 = lane & 15, lg = lane >> 4;
  const int tile_t = unit >> 1;
  const int ib = (unit & 1) * 2;

  short8 kf[2];
  #pragma unroll
  for (int j = 0; j < 2; ++j)
    kf[j] = *(const short8*)(kfb + (((size_t)(b * 32 + tile_t)) * 4 + ib + j) * 512 + lane * 8);

  const __hip_bfloat16* qp = qfb + (size_t)b * 32 * 2048;
  const f32x4 z = {0.f, 0.f, 0.f, 0.f};
  f32x4 s0 = z, s1 = z;

  QT A, B;
  loadQ(A, qp, 0, lane);
  for (int it2 = 0; it2 < 16; ++it2) {
    const int itA = it2 * 2;
    loadQ(B, qp, itA + 1, lane);
    SCHEDW;                         // pin B's loads: issue HERE, wait at use
    accQ(A, kf[0], kf[1], s0, s1);
    loadQ(A, qp, itA + 2 < 32 ? itA + 2 : 31, lane);
    SCHEDW;
    accQ(B, kf[0], kf[1], s0, s1);
  }
  #pragma unroll
  for (int m = 1; m < 16; m <<= 1) {
    #pragma unroll
    for (int r = 0; r < 4; ++r) {
      s0[r] += __shfl_xor(s0[r], m);
      s1[r] += __shfl_xor(s1[r], m);
    }
  }
  if (l15 == 0) {
    f32x4 o0, o1;
    #pragma unroll
    for (int r = 0; r < 4; ++r) { o0[r] = -__log2f(s0[r]); o1[r] = -__log2f(s1[r]); }
    float* lp = ls + ((size_t)b << 11) + tile_t * 64 + ib * 16 + lg * 4;
    *(f32x4*)(lp) = o0;
    *(f32x4*)(lp + 16) = o1;
  }
}

// ---------------- Kernel 3: attn — 1-wave blocks, per-qi P buffers ----------
struct KVT {
  short8 k0, k1, k2, k3;
  short8 v0, v1, v2, v3;
  f32x4 l0, l1, l2, l3;
};

__device__ __forceinline__ void loadKV(KVT& t, const __hip_bfloat16* kp0,
    const __hip_bfloat16* vp0, const float* lsb, int it, int lane, int lg) {
  const __hip_bfloat16* kp = kp0 + (size_t)it * 2048 + lane * 8;
  t.k0 = *(const short8*)(kp);
  t.k1 = *(const short8*)(kp + 512);
  t.k2 = *(const short8*)(kp + 1024);
  t.k3 = *(const short8*)(kp + 1536);
  const __hip_bfloat16* vp = vp0 + (size_t)it * 2048 + lane * 8;
  t.v0 = *(const short8*)(vp);
  t.v1 = *(const short8*)(vp + 512);
  t.v2 = *(const short8*)(vp + 1024);
  t.v3 = *(const short8*)(vp + 1536);
  const float* lp = lsb + it * 64 + lg * 4;
  t.l0 = *(const f32x4*)(lp);
  t.l1 = *(const f32x4*)(lp + 16);
  t.l2 = *(const f32x4*)(lp + 32);
  t.l3 = *(const f32x4*)(lp + 48);
}

// per-qi P buffer: 16 rows (q) x 176 B. Separate buffers let the two qi
// dependency chains interleave (no write-after-read ordering between them).
__device__ __forceinline__ void computeKV(const KVT& t, short8 qf, char* Pw,
                                          int lg, f32x4& h10, f32x4& h11) {
  f32x4 d;
  uint2 w;
  d = __builtin_amdgcn_mfma_f32_16x16x32_bf16(t.k0, qf, t.l0, 0, 0, 0);
  w.x = pk2(fexp2(d[0]), fexp2(d[1]));
  w.y = pk2(fexp2(d[2]), fexp2(d[3]));
  *(uint2*)(Pw + lg * 8) = w;
  d = __builtin_amdgcn_mfma_f32_16x16x32_bf16(t.k1, qf, t.l1, 0, 0, 0);
  w.x = pk2(fexp2(d[0]), fexp2(d[1]));
  w.y = pk2(fexp2(d[2]), fexp2(d[3]));
  *(uint2*)(Pw + 32 + lg * 8) = w;
  d = __builtin_amdgcn_mfma_f32_16x16x32_bf16(t.k2, qf, t.l2, 0, 0, 0);
  w.x = pk2(fexp2(d[0]), fexp2(d[1]));
  w.y = pk2(fexp2(d[2]), fexp2(d[3]));
  *(uint2*)(Pw + 64 + lg * 8) = w;
  d = __builtin_amdgcn_mfma_f32_16x16x32_bf16(t.k3, qf, t.l3, 0, 0, 0);
  w.x = pk2(fexp2(d[0]), fexp2(d[1]));
  w.y = pk2(fexp2(d[2]), fexp2(d[3]));
  *(uint2*)(Pw + 96 + lg * 8) = w;
  LFENCE;  // pin P ds_write -> ds_read order (same wave, in-order DS pipe)
  const short8 p0 = *(const short8*)(Pw + lg * 16);
  const short8 p1 = *(const short8*)(Pw + 64 + lg * 16);
  h10 = __builtin_amdgcn_mfma_f32_16x16x32_bf16(p0, t.v0, h10, 0, 0, 0);
  h11 = __builtin_amdgcn_mfma_f32_16x16x32_bf16(p0, t.v1, h11, 0, 0, 0);
  h10 = __builtin_amdgcn_mfma_f32_16x16x32_bf16(p1, t.v2, h10, 0, 0, 0);
  h11 = __builtin_amdgcn_mfma_f32_16x16x32_bf16(p1, t.v3, h11, 0, 0, 0);
  LFENCE;  // keep this buffer's next-tile writes after these reads
}

__global__ __launch_bounds__(64) void attn_kernel(
    const __hip_bfloat16* __restrict__ qfb, const __hip_bfloat16* __restrict__ kfb,
    const __hip_bfloat16* __restrict__ vfb, const float* __restrict__ ls,
    const __hip_bfloat16* __restrict__ whT, float* __restrict__ out) {
  __shared__ char Ps[2 * 2816];   // 2 P buffers (one per qi) x 16 rows x 176 B

  const int g = blockIdx.x;
  const int xcd = g & 7, loc = g >> 3;      // 2048 = 8 xcd * 256
  const int b = (xcd << 2) + (loc >> 6);
  const int unit = loc & 63;                // wave-unit: 2 q-frags (32 q)
  const int lane = threadIdx.x;
  const int l15 = lane & 15, lg = lane >> 4;
  const int tile_q = unit >> 1;
  const int ib = (unit & 1) * 2;

  char* Pw0 = Ps + l15 * 176;
  char* Pw1 = Ps + 2816 + l15 * 176;

  short8 qf[2];
  #pragma unroll
  for (int qi = 0; qi < 2; ++qi)
    qf[qi] = *(const short8*)(qfb + (((size_t)(b * 32 + tile_q)) * 4 + ib + qi) * 512 + lane * 8);

  const __hip_bfloat16* kp0 = kfb + (size_t)b * 32 * 2048;
  const __hip_bfloat16* vp0 = vfb + (size_t)b * 32 * 2048;
  const float* lsb = ls + ((size_t)b << 11);

  const f32x4 z = {0.f, 0.f, 0.f, 0.f};
  f32x4 h1[2][2] = {{z, z}, {z, z}};

  KVT A, B;
  loadKV(A, kp0, vp0, lsb, 0, lane, lg);
  SCHEDW;
  for (int it2 = 0; it2 < 16; ++it2) {
    const int itA = it2 * 2;
    loadKV(B, kp0, vp0, lsb, itA + 1, lane, lg);
    SCHEDW;                         // pin B's loads: issue HERE, wait at use
    computeKV(A, qf[0], Pw0, lg, h1[0][0], h1[0][1]);
    computeKV(A, qf[1], Pw1, lg, h1[1][0], h1[1][1]);
    loadKV(A, kp0, vp0, lsb, itA + 2 < 32 ? itA + 2 : 31, lane, lg);
    SCHEDW;                         // pin A's next-tile loads
    computeKV(B, qf[0], Pw0, lg, h1[0][0], h1[0][1]);
    computeKV(B, qf[1], Pw1, lg, h1[1][0], h1[1][1]);
  }

  // epilogue: out = h1 @ Wh per q-frag (single wave, no barrier needed)
  short8 wf[4];
  #pragma unroll
  for (int dt = 0; dt < 4; ++dt)
    wf[dt] = *(const short8*)(whT + dt * 512 + lane * 8);
  #pragma unroll
  for (int qi = 0; qi < 2; ++qi) {
    #pragma unroll
    for (int vs = 0; vs < 2; ++vs)
      #pragma unroll
      for (int r = 0; r < 4; ++r)
        *(unsigned short*)(Ps + (lg * 4 + r) * 176 + (vs * 16 + l15) * 2) =
            __builtin_bit_cast(unsigned short, __float2bfloat16(h1[qi][vs][r]));
    LFENCE;
    const short8 hf = *(const short8*)(Pw0 + lg * 16);
    float* ob = out + (size_t)(b * NS + tile_q * 64 + (ib + qi) * 16 + lg * 4) * ND + l15;
    #pragma unroll
    for (int dt = 0; dt < 4; ++dt) {
      f32x4 o = __builtin_amdgcn_mfma_f32_16x16x32_bf16(hf, wf[dt], z, 0, 0, 0);
      float* op = ob + dt * 16;
      op[0] = o[0];
      op[ND] = o[1];
      op[2 * ND] = o[2];
      op[3 * ND] = o[3];
    }
    LFENCE;
  }
}

// ---------------- launcher ----------------
extern "C" void kernel_launch(void* const* d_in, const int* in_sizes, int n_in,
                              void* d_out, int out_size, void* d_ws, size_t ws_size,
                              hipStream_t stream) {
  const float* x  = (const float*)d_in[0];
  const float* Wq = (const float*)d_in[1];
  const float* Wk = (const float*)d_in[2];
  const float* Wv = (const float*)d_in[3];
  const float* Wh = (const float*)d_in[4];
  float* out = (float*)d_out;

  char* ws = (char*)d_ws;
  __hip_bfloat16* qfb = (__hip_bfloat16*)ws;                   // 4 MB
  __hip_bfloat16* kfb = (__hip_bfloat16*)(ws + 4194304);       // 4 MB
  __hip_bfloat16* vfb = (__hip_bfloat16*)(ws + 8388608);       // 4 MB
  float*          lsp = (float*)(ws + 12582912);               // 256 KB
  __hip_bfloat16* whT = (__hip_bfloat16*)(ws + 12845056);      // 4 KB
  __hip_bfloat16* wt  = (__hip_bfloat16*)(ws + 12849152);      // 12 KB

  hipLaunchKernelGGL(prep_kernel, dim3(1), dim3(256), 0, stream,
                     Wq, Wk, Wv, Wh, wt, whT);
  hipLaunchKernelGGL(proj_kernel, dim3(1024), dim3(256), 0, stream,
                     x, wt, qfb, kfb, vfb);
  hipLaunchKernelGGL(stats_kernel, dim3(2048), dim3(64), 0, stream,
                     qfb, kfb, lsp);
  hipLaunchKernelGGL(attn_kernel, dim3(2048), dim3(64), 0, stream,
                     qfb, kfb, vfb, lsp, whT, out);
}